// Round 1
// baseline (1885.957 us; speedup 1.0000x reference)
//
#include <hip/hip_runtime.h>

#define T_STEPS 512
#define NDIM    512
#define DDIM    64
#define BBATCH  256
#define WLDS_STRIDE 136   // 128 k-halves + 8 pad (272B row: 16B-aligned, bank-spread)
#define XLDS_STRIDE 520   // 512 + 8 pad (1040B row: 16B-aligned, bank-spread)
#define RF_OFF  0         // W_res reg-fragment region (halves) in tail
#define WI_OFF  196608    // W_in fragment region (halves) in tail

typedef _Float16 half8 __attribute__((ext_vector_type(8)));
typedef _Float16 half4 __attribute__((ext_vector_type(4)));
typedef float    f32x4 __attribute__((ext_vector_type(4)));

__device__ __forceinline__ float tanh_fast(float x) {
    // tanh(x) = 1 - 2/(e^{2x}+1). No clamp needed: exp2->inf => rcp->0 => +1;
    // exp2->0 => 1-2 = -1. Graceful at both rails.
    float e = __builtin_amdgcn_exp2f(x * 2.885390081777927f);   // e^(2x)
    return 1.f - 2.f * __builtin_amdgcn_rcpf(e + 1.f);
}

// Raw workgroup barrier: drains LDS ops only (lgkmcnt), NOT the global-store /
// prefetch queue (vmcnt). __syncthreads() would emit s_waitcnt vmcnt(0) and
// serially eat an L2 store-ack round trip every step. sched_barrier(0) fences
// stop hipcc hoisting ds ops across the inline asm (rule #18).
#define LGKM_BARRIER() do {                                        \
    __builtin_amdgcn_sched_barrier(0);                             \
    asm volatile("s_waitcnt lgkmcnt(0)" ::: "memory");             \
    __builtin_amdgcn_s_barrier();                                  \
    __builtin_amdgcn_sched_barrier(0);                             \
} while (0)

// ---------------------------------------------------------------------------
// prep: gather fp16 MFMA fragments of W_res (k-tiles 4..15) and W_in into the
// d_out tail (final-state region; overwritten with real output at t=511).
// Fragment data for lane L: value[j] = W[k0 + (L>>4)*8 + j][ntg*16 + (L&15)].
// ---------------------------------------------------------------------------
__global__ void prep_kernel(const float* __restrict__ W_in,
                            const float* __restrict__ W_res,
                            _Float16* __restrict__ tail) {
    int id0 = blockIdx.x * blockDim.x + threadIdx.x;
    int stride = gridDim.x * blockDim.x;
    for (int id = id0; id < 12 * 32 * 64; id += stride) {       // W_res frags
        int ktr = id >> 11, rem = id & 2047;
        int ctg = rem >> 6, lane = rem & 63;
        int q = lane >> 4, c = lane & 15;
        int k0 = (ktr + 4) * 32 + q * 8;
        int n  = ctg * 16 + c;
        half8 v;
        #pragma unroll
        for (int j = 0; j < 8; ++j) v[j] = (_Float16)W_res[(size_t)(k0 + j) * NDIM + n];
        *(half8*)(tail + RF_OFF + (size_t)id * 8) = v;
    }
    for (int id = id0; id < 2 * 32 * 64; id += stride) {        // W_in frags
        int idx = id >> 6, lane = id & 63;
        int ktu = idx >> 5, ntg = idx & 31;
        int q = lane >> 4, c = lane & 15;
        int k0 = ktu * 32 + q * 8;
        int n  = ntg * 16 + c;
        half8 v;
        #pragma unroll
        for (int j = 0; j < 8; ++j) v[j] = (_Float16)W_in[(size_t)(k0 + j) * NDIM + n];
        *(half8*)(tail + WI_OFF + (size_t)id * 8) = v;
    }
}

// ---------------------------------------------------------------------------
// u_kernel: U = inputs @ W_in + b_in (+ b_res for all rows with t != 0),
// written into the X region of d_out. Folding b_res here removes the per-step
// br_lds broadcast read + add from the scan's serial inner loop.
// ---------------------------------------------------------------------------
__global__ __launch_bounds__(256) void u_kernel(const float* __restrict__ inputs,
                                                const float* __restrict__ b_in,
                                                const float* __restrict__ b_res,
                                                const _Float16* __restrict__ tail,
                                                float* __restrict__ U) {
    __shared__ _Float16 in_s[64 * 72];
    int tid = threadIdx.x;
    int w = tid >> 6, lane = tid & 63, q = lane >> 4, c = lane & 15;
    int row_base = blockIdx.x * 64;

    for (int i = tid; i < 1024; i += 256) {                     // stage 64x64 fp32 -> fp16
        f32x4 v = *(const f32x4*)(inputs + (size_t)row_base * DDIM + (size_t)i * 4);
        int row = i >> 4, d4 = (i & 15) * 4;
        half4 h; h[0]=(_Float16)v[0]; h[1]=(_Float16)v[1]; h[2]=(_Float16)v[2]; h[3]=(_Float16)v[3];
        *(half4*)(in_s + row * 72 + d4) = h;
    }
    __syncthreads();

    half8 a0 = *(const half8*)(in_s + (w * 16 + c) * 72 + q * 8);
    half8 a1 = *(const half8*)(in_s + (w * 16 + c) * 72 + 32 + q * 8);
    int row = row_base + w * 16 + q * 4;
    #pragma unroll 4
    for (int ntg = 0; ntg < 32; ++ntg) {
        int n = ntg * 16 + c;
        half8 b0 = *(const half8*)(tail + WI_OFF + ((size_t)ntg * 64 + lane) * 8);
        half8 b1 = *(const half8*)(tail + WI_OFF + ((size_t)(32 + ntg) * 64 + lane) * 8);
        float bv  = b_in[n];
        float brv = b_res[n];
        f32x4 acc = {bv, bv, bv, bv};
        acc = __builtin_amdgcn_mfma_f32_16x16x32_f16(a0, b0, acc, 0, 0, 0);
        acc = __builtin_amdgcn_mfma_f32_16x16x32_f16(a1, b1, acc, 0, 0, 0);
        #pragma unroll
        for (int r = 0; r < 4; ++r) {
            float o = acc[r] + ((((row + r) & (T_STEPS - 1)) != 0) ? brv : 0.f);
            U[(size_t)(row + r) * NDIM + n] = o;
        }
    }
}

// ---------------------------------------------------------------------------
// scan: 16 persistent blocks (one CU each), 512 threads (8 waves).
// Block owns 16 batches. W_res fp16: k-tiles 0..3 in LDS, 4..15 in registers.
// Transposed MFMA: D[m=ncol][n=batch] = W_res^T (A) x^T (B) -> each lane gets
// 4 consecutive n-cols of one batch => b64 LDS publish, dwordx4 global I/O.
// Changes this round: raw lgkm-only barriers (no vmcnt drain of X stores /
// U prefetch), x_prev kept in registers (no epilogue LDS read), b_res
// pre-folded into U, clamp-free tanh.
// ---------------------------------------------------------------------------
__global__ __launch_bounds__(512, 2) void scan_kernel(
        const float* __restrict__ W_res,
        const _Float16* __restrict__ tail, float* __restrict__ out) {
    __shared__ _Float16 W_lds[NDIM * WLDS_STRIDE];   // [ncol][k'] k' in [0,128)
    __shared__ _Float16 x_lds[16 * XLDS_STRIDE];     // [batch][k=ncol] fp16 state

    int tid = threadIdx.x;
    int w = tid >> 6, lane = tid & 63, q = lane >> 4, c = lane & 15;
    int b0 = blockIdx.x * 16;

    for (int idx = tid; idx < 128 * NDIM; idx += 512) {          // W_res k<128 -> LDS
        int k = idx >> 9, n = idx & 511;
        W_lds[n * WLDS_STRIDE + k] = (_Float16)W_res[idx];
    }
    for (int i = tid; i < 16 * XLDS_STRIDE; i += 512) x_lds[i] = (_Float16)0.f;

    half8 wreg[12][4];                                           // W_res k-tiles 4..15
    #pragma unroll
    for (int ktr = 0; ktr < 12; ++ktr)
        #pragma unroll
        for (int mt = 0; mt < 4; ++mt)
            wreg[ktr][mt] = *(const half8*)(tail + RF_OFF +
                ((size_t)(ktr * 32 + (w * 4 + mt)) * 64 + lane) * 8);

    int batch = b0 + c;                 // batch this lane's acc column maps to
    int nbase = w * 64 + q * 4;         // + mt*16 + r = global n-col
    size_t outb = (size_t)batch * T_STEPS * NDIM;

    f32x4 Upre[4];
    #pragma unroll
    for (int mt = 0; mt < 4; ++mt)
        Upre[mt] = *(const f32x4*)(out + outb + nbase + mt * 16);   // U[b][0][*]

    half4 xprev[4];                     // this lane's own x state (fp16-rounded,
    #pragma unroll                      // identical to what the LDS round-trip gave)
    for (int mt = 0; mt < 4; ++mt)
        #pragma unroll
        for (int r = 0; r < 4; ++r) xprev[mt][r] = (_Float16)0.f;

    __syncthreads();

    for (int t = 0; t < T_STEPS; ++t) {
        f32x4 acc[4];
        #pragma unroll
        for (int mt = 0; mt < 4; ++mt) acc[mt] = Upre[mt];       // b_res pre-folded
        if (t < T_STEPS - 1) {                                   // prefetch U[t+1]
            #pragma unroll
            for (int mt = 0; mt < 4; ++mt)
                Upre[mt] = *(const f32x4*)(out + outb + (size_t)(t + 1) * NDIM + nbase + mt * 16);
        }
        #pragma unroll
        for (int kt = 0; kt < 4; ++kt) {                         // LDS-resident k-tiles
            half8 xb = *(const half8*)(x_lds + c * XLDS_STRIDE + kt * 32 + q * 8);
            #pragma unroll
            for (int mt = 0; mt < 4; ++mt) {
                half8 a = *(const half8*)(W_lds +
                    (size_t)((w * 4 + mt) * 16 + c) * WLDS_STRIDE + kt * 32 + q * 8);
                acc[mt] = __builtin_amdgcn_mfma_f32_16x16x32_f16(a, xb, acc[mt], 0, 0, 0);
            }
        }
        #pragma unroll
        for (int ktr = 0; ktr < 12; ++ktr) {                     // register k-tiles
            half8 xb = *(const half8*)(x_lds + c * XLDS_STRIDE + (ktr + 4) * 32 + q * 8);
            #pragma unroll
            for (int mt = 0; mt < 4; ++mt)
                acc[mt] = __builtin_amdgcn_mfma_f32_16x16x32_f16(wreg[ktr][mt], xb, acc[mt], 0, 0, 0);
        }
        // epilogue: blend + tanh; store X; x_prev stays in registers
        #pragma unroll
        for (int mt = 0; mt < 4; ++mt) {
            f32x4 xn;
            #pragma unroll
            for (int r = 0; r < 4; ++r)
                xn[r] = 0.5f * ((float)xprev[mt][r] + tanh_fast(acc[mt][r]));
            *(f32x4*)(out + outb + (size_t)t * NDIM + nbase + mt * 16) = xn;
            if (t == T_STEPS - 1)
                *(f32x4*)(out + (size_t)BBATCH * T_STEPS * NDIM +
                          (size_t)batch * NDIM + nbase + mt * 16) = xn;
            #pragma unroll
            for (int r = 0; r < 4; ++r) xprev[mt][r] = (_Float16)xn[r];
        }
        LGKM_BARRIER();                                           // all reads of x done
        #pragma unroll
        for (int mt = 0; mt < 4; ++mt)
            *(half4*)(x_lds + c * XLDS_STRIDE + nbase + mt * 16) = xprev[mt];
        LGKM_BARRIER();                                           // x published
    }
}

extern "C" void kernel_launch(void* const* d_in, const int* in_sizes, int n_in,
                              void* d_out, int out_size, void* d_ws, size_t ws_size,
                              hipStream_t stream) {
    const float* inputs = (const float*)d_in[0];
    const float* W_in   = (const float*)d_in[1];
    const float* b_in   = (const float*)d_in[2];
    const float* W_res  = (const float*)d_in[3];
    const float* b_res  = (const float*)d_in[4];
    float* out = (float*)d_out;
    // fragment scratch lives in the final-state tail of d_out (rewritten at t=511)
    _Float16* tail = (_Float16*)(out + (size_t)BBATCH * T_STEPS * NDIM);

    prep_kernel<<<96, 256, 0, stream>>>(W_in, W_res, tail);
    u_kernel<<<(BBATCH * T_STEPS) / 64, 256, 0, stream>>>(inputs, b_in, b_res, tail, out);
    scan_kernel<<<BBATCH / 16, 512, 0, stream>>>(W_res, tail, out);
}

// Round 2
// 1817.008 us; speedup vs baseline: 1.0379x; 1.0379x over previous
//
#include <hip/hip_runtime.h>

#define T_STEPS 512
#define NDIM    512
#define DDIM    64
#define BBATCH  256
#define WLDS_STRIDE 136   // 128 k-halves + 8 pad (272B row: 16B-aligned, bank-spread)
#define XLDS_STRIDE 520   // 512 + 8 pad (1040B row: 16B-aligned, bank-spread)
#define RF_OFF  0         // W_res reg-fragment region (halves) in tail
#define WI_OFF  196608    // W_in fragment region (halves) in tail

typedef _Float16 half8 __attribute__((ext_vector_type(8)));
typedef _Float16 half4 __attribute__((ext_vector_type(4)));
typedef float    f32x4 __attribute__((ext_vector_type(4)));

__device__ __forceinline__ float tanh_fast(float x) {
    // tanh(x) = 1 - 2/(e^{2x}+1). No clamp needed: exp2->inf => rcp->0 => +1;
    // exp2->0 => 1-2 = -1. Graceful at both rails.
    float e = __builtin_amdgcn_exp2f(x * 2.885390081777927f);   // e^(2x)
    return 1.f - 2.f * __builtin_amdgcn_rcpf(e + 1.f);
}

// ---------------------------------------------------------------------------
// prep: gather fp16 MFMA fragments of W_res (k-tiles 4..15) and W_in into the
// d_out tail (final-state region; overwritten with real output at t=511).
// Fragment data for lane L: value[j] = W[k0 + (L>>4)*8 + j][ntg*16 + (L&15)].
// ---------------------------------------------------------------------------
__global__ void prep_kernel(const float* __restrict__ W_in,
                            const float* __restrict__ W_res,
                            _Float16* __restrict__ tail) {
    int id0 = blockIdx.x * blockDim.x + threadIdx.x;
    int stride = gridDim.x * blockDim.x;
    for (int id = id0; id < 12 * 32 * 64; id += stride) {       // W_res frags
        int ktr = id >> 11, rem = id & 2047;
        int ctg = rem >> 6, lane = rem & 63;
        int q = lane >> 4, c = lane & 15;
        int k0 = (ktr + 4) * 32 + q * 8;
        int n  = ctg * 16 + c;
        half8 v;
        #pragma unroll
        for (int j = 0; j < 8; ++j) v[j] = (_Float16)W_res[(size_t)(k0 + j) * NDIM + n];
        *(half8*)(tail + RF_OFF + (size_t)id * 8) = v;
    }
    for (int id = id0; id < 2 * 32 * 64; id += stride) {        // W_in frags
        int idx = id >> 6, lane = id & 63;
        int ktu = idx >> 5, ntg = idx & 31;
        int q = lane >> 4, c = lane & 15;
        int k0 = ktu * 32 + q * 8;
        int n  = ntg * 16 + c;
        half8 v;
        #pragma unroll
        for (int j = 0; j < 8; ++j) v[j] = (_Float16)W_in[(size_t)(k0 + j) * NDIM + n];
        *(half8*)(tail + WI_OFF + (size_t)id * 8) = v;
    }
}

// ---------------------------------------------------------------------------
// u_kernel: U = inputs @ W_in + b_in (+ b_res for all rows with t != 0),
// written into the X region of d_out. Folding b_res here removes the per-step
// br_lds broadcast read + add from the scan's serial inner loop.
// ---------------------------------------------------------------------------
__global__ __launch_bounds__(256) void u_kernel(const float* __restrict__ inputs,
                                                const float* __restrict__ b_in,
                                                const float* __restrict__ b_res,
                                                const _Float16* __restrict__ tail,
                                                float* __restrict__ U) {
    __shared__ _Float16 in_s[64 * 72];
    int tid = threadIdx.x;
    int w = tid >> 6, lane = tid & 63, q = lane >> 4, c = lane & 15;
    int row_base = blockIdx.x * 64;

    for (int i = tid; i < 1024; i += 256) {                     // stage 64x64 fp32 -> fp16
        f32x4 v = *(const f32x4*)(inputs + (size_t)row_base * DDIM + (size_t)i * 4);
        int row = i >> 4, d4 = (i & 15) * 4;
        half4 h; h[0]=(_Float16)v[0]; h[1]=(_Float16)v[1]; h[2]=(_Float16)v[2]; h[3]=(_Float16)v[3];
        *(half4*)(in_s + row * 72 + d4) = h;
    }
    __syncthreads();

    half8 a0 = *(const half8*)(in_s + (w * 16 + c) * 72 + q * 8);
    half8 a1 = *(const half8*)(in_s + (w * 16 + c) * 72 + 32 + q * 8);
    int row = row_base + w * 16 + q * 4;
    #pragma unroll 4
    for (int ntg = 0; ntg < 32; ++ntg) {
        int n = ntg * 16 + c;
        half8 b0 = *(const half8*)(tail + WI_OFF + ((size_t)ntg * 64 + lane) * 8);
        half8 b1 = *(const half8*)(tail + WI_OFF + ((size_t)(32 + ntg) * 64 + lane) * 8);
        float bv  = b_in[n];
        float brv = b_res[n];
        f32x4 acc = {bv, bv, bv, bv};
        acc = __builtin_amdgcn_mfma_f32_16x16x32_f16(a0, b0, acc, 0, 0, 0);
        acc = __builtin_amdgcn_mfma_f32_16x16x32_f16(a1, b1, acc, 0, 0, 0);
        #pragma unroll
        for (int r = 0; r < 4; ++r) {
            float o = acc[r] + ((((row + r) & (T_STEPS - 1)) != 0) ? brv : 0.f);
            U[(size_t)(row + r) * NDIM + n] = o;
        }
    }
}

// ---------------------------------------------------------------------------
// scan: 16 persistent blocks (one CU each), 512 threads (8 waves).
// Block owns 16 batches. W_res fp16: k-tiles 0..3 in LDS, 4..15 in registers.
// Transposed MFMA: D[m=ncol][n=batch] = W_res^T (A) x^T (B) -> each lane gets
// 4 consecutive n-cols of one batch => b64 LDS publish, dwordx4 global I/O.
// Round-2 A/B: plain __syncthreads() restored (round-1's lgkm-only barrier
// regressed 32%: the vmcnt(0) drain is a per-step wave phase-lock, not dead
// time — without it 8 waves drift, the barrier collects max-of-8 tail
// latencies twice per step). Keeping: xprev-in-registers, b_res folded into
// U, clamp-free tanh.
// ---------------------------------------------------------------------------
__global__ __launch_bounds__(512, 2) void scan_kernel(
        const float* __restrict__ W_res,
        const _Float16* __restrict__ tail, float* __restrict__ out) {
    __shared__ _Float16 W_lds[NDIM * WLDS_STRIDE];   // [ncol][k'] k' in [0,128)
    __shared__ _Float16 x_lds[16 * XLDS_STRIDE];     // [batch][k=ncol] fp16 state

    int tid = threadIdx.x;
    int w = tid >> 6, lane = tid & 63, q = lane >> 4, c = lane & 15;
    int b0 = blockIdx.x * 16;

    for (int idx = tid; idx < 128 * NDIM; idx += 512) {          // W_res k<128 -> LDS
        int k = idx >> 9, n = idx & 511;
        W_lds[n * WLDS_STRIDE + k] = (_Float16)W_res[idx];
    }
    for (int i = tid; i < 16 * XLDS_STRIDE; i += 512) x_lds[i] = (_Float16)0.f;

    half8 wreg[12][4];                                           // W_res k-tiles 4..15
    #pragma unroll
    for (int ktr = 0; ktr < 12; ++ktr)
        #pragma unroll
        for (int mt = 0; mt < 4; ++mt)
            wreg[ktr][mt] = *(const half8*)(tail + RF_OFF +
                ((size_t)(ktr * 32 + (w * 4 + mt)) * 64 + lane) * 8);

    int batch = b0 + c;                 // batch this lane's acc column maps to
    int nbase = w * 64 + q * 4;         // + mt*16 + r = global n-col
    size_t outb = (size_t)batch * T_STEPS * NDIM;

    f32x4 Upre[4];
    #pragma unroll
    for (int mt = 0; mt < 4; ++mt)
        Upre[mt] = *(const f32x4*)(out + outb + nbase + mt * 16);   // U[b][0][*]

    half4 xprev[4];                     // this lane's own x state (fp16-rounded,
    #pragma unroll                      // identical to what the LDS round-trip gave)
    for (int mt = 0; mt < 4; ++mt)
        #pragma unroll
        for (int r = 0; r < 4; ++r) xprev[mt][r] = (_Float16)0.f;

    __syncthreads();

    for (int t = 0; t < T_STEPS; ++t) {
        f32x4 acc[4];
        #pragma unroll
        for (int mt = 0; mt < 4; ++mt) acc[mt] = Upre[mt];       // b_res pre-folded
        if (t < T_STEPS - 1) {                                   // prefetch U[t+1]
            #pragma unroll
            for (int mt = 0; mt < 4; ++mt)
                Upre[mt] = *(const f32x4*)(out + outb + (size_t)(t + 1) * NDIM + nbase + mt * 16);
        }
        #pragma unroll
        for (int kt = 0; kt < 4; ++kt) {                         // LDS-resident k-tiles
            half8 xb = *(const half8*)(x_lds + c * XLDS_STRIDE + kt * 32 + q * 8);
            #pragma unroll
            for (int mt = 0; mt < 4; ++mt) {
                half8 a = *(const half8*)(W_lds +
                    (size_t)((w * 4 + mt) * 16 + c) * WLDS_STRIDE + kt * 32 + q * 8);
                acc[mt] = __builtin_amdgcn_mfma_f32_16x16x32_f16(a, xb, acc[mt], 0, 0, 0);
            }
        }
        #pragma unroll
        for (int ktr = 0; ktr < 12; ++ktr) {                     // register k-tiles
            half8 xb = *(const half8*)(x_lds + c * XLDS_STRIDE + (ktr + 4) * 32 + q * 8);
            #pragma unroll
            for (int mt = 0; mt < 4; ++mt)
                acc[mt] = __builtin_amdgcn_mfma_f32_16x16x32_f16(wreg[ktr][mt], xb, acc[mt], 0, 0, 0);
        }
        // epilogue: blend + tanh; store X; x_prev stays in registers
        #pragma unroll
        for (int mt = 0; mt < 4; ++mt) {
            f32x4 xn;
            #pragma unroll
            for (int r = 0; r < 4; ++r)
                xn[r] = 0.5f * ((float)xprev[mt][r] + tanh_fast(acc[mt][r]));
            *(f32x4*)(out + outb + (size_t)t * NDIM + nbase + mt * 16) = xn;
            if (t == T_STEPS - 1)
                *(f32x4*)(out + (size_t)BBATCH * T_STEPS * NDIM +
                          (size_t)batch * NDIM + nbase + mt * 16) = xn;
            #pragma unroll
            for (int r = 0; r < 4; ++r) xprev[mt][r] = (_Float16)xn[r];
        }
        __syncthreads();                                          // all reads of x done
        #pragma unroll
        for (int mt = 0; mt < 4; ++mt)
            *(half4*)(x_lds + c * XLDS_STRIDE + nbase + mt * 16) = xprev[mt];
        __syncthreads();                                          // x published
    }
}

extern "C" void kernel_launch(void* const* d_in, const int* in_sizes, int n_in,
                              void* d_out, int out_size, void* d_ws, size_t ws_size,
                              hipStream_t stream) {
    const float* inputs = (const float*)d_in[0];
    const float* W_in   = (const float*)d_in[1];
    const float* b_in   = (const float*)d_in[2];
    const float* W_res  = (const float*)d_in[3];
    const float* b_res  = (const float*)d_in[4];
    float* out = (float*)d_out;
    // fragment scratch lives in the final-state tail of d_out (rewritten at t=511)
    _Float16* tail = (_Float16*)(out + (size_t)BBATCH * T_STEPS * NDIM);

    prep_kernel<<<96, 256, 0, stream>>>(W_in, W_res, tail);
    u_kernel<<<(BBATCH * T_STEPS) / 64, 256, 0, stream>>>(inputs, b_in, b_res, tail, out);
    scan_kernel<<<BBATCH / 16, 512, 0, stream>>>(W_res, tail, out);
}

// Round 3
// 1419.008 us; speedup vs baseline: 1.3291x; 1.2805x over previous
//
#include <hip/hip_runtime.h>

#define T_STEPS 512
#define NDIM    512
#define DDIM    64
#define BBATCH  256
#define BPB     8         // batches per scan block (was 16): halves per-CU VMEM stream
#define WLDS_STRIDE 136   // 128 k-halves + 8 pad (272B row: 16B-aligned, bank-spread)
#define XLDS_STRIDE 520   // 512 + 8 pad (1040B row: 16B-aligned, bank-spread)
#define RF_OFF  0         // W_res reg-fragment region (halves) in tail
#define WI_OFF  196608    // W_in fragment region (halves) in tail

typedef _Float16 half8 __attribute__((ext_vector_type(8)));
typedef _Float16 half4 __attribute__((ext_vector_type(4)));
typedef float    f32x4 __attribute__((ext_vector_type(4)));

__device__ __forceinline__ float tanh_fast(float x) {
    // tanh(x) = 1 - 2/(e^{2x}+1). exp2->inf => rcp->0 => +1; exp2->0 => -1.
    float e = __builtin_amdgcn_exp2f(x * 2.885390081777927f);   // e^(2x)
    return 1.f - 2.f * __builtin_amdgcn_rcpf(e + 1.f);
}

// ---------------------------------------------------------------------------
// prep: gather fp16 MFMA fragments of W_res (k-tiles 4..15) and W_in into the
// d_out tail (final-state region; overwritten with real output at t=511).
// Fragment data for lane L: value[j] = W[k0 + (L>>4)*8 + j][ntg*16 + (L&15)].
// ---------------------------------------------------------------------------
__global__ void prep_kernel(const float* __restrict__ W_in,
                            const float* __restrict__ W_res,
                            _Float16* __restrict__ tail) {
    int id0 = blockIdx.x * blockDim.x + threadIdx.x;
    int stride = gridDim.x * blockDim.x;
    for (int id = id0; id < 12 * 32 * 64; id += stride) {       // W_res frags
        int ktr = id >> 11, rem = id & 2047;
        int ctg = rem >> 6, lane = rem & 63;
        int q = lane >> 4, c = lane & 15;
        int k0 = (ktr + 4) * 32 + q * 8;
        int n  = ctg * 16 + c;
        half8 v;
        #pragma unroll
        for (int j = 0; j < 8; ++j) v[j] = (_Float16)W_res[(size_t)(k0 + j) * NDIM + n];
        *(half8*)(tail + RF_OFF + (size_t)id * 8) = v;
    }
    for (int id = id0; id < 2 * 32 * 64; id += stride) {        // W_in frags
        int idx = id >> 6, lane = id & 63;
        int ktu = idx >> 5, ntg = idx & 31;
        int q = lane >> 4, c = lane & 15;
        int k0 = ktu * 32 + q * 8;
        int n  = ntg * 16 + c;
        half8 v;
        #pragma unroll
        for (int j = 0; j < 8; ++j) v[j] = (_Float16)W_in[(size_t)(k0 + j) * NDIM + n];
        *(half8*)(tail + WI_OFF + (size_t)id * 8) = v;
    }
}

// ---------------------------------------------------------------------------
// u_kernel: U = inputs @ W_in + b_in (+ b_res for all rows with t != 0),
// written into the X region of d_out.
// ---------------------------------------------------------------------------
__global__ __launch_bounds__(256) void u_kernel(const float* __restrict__ inputs,
                                                const float* __restrict__ b_in,
                                                const float* __restrict__ b_res,
                                                const _Float16* __restrict__ tail,
                                                float* __restrict__ U) {
    __shared__ _Float16 in_s[64 * 72];
    int tid = threadIdx.x;
    int w = tid >> 6, lane = tid & 63, q = lane >> 4, c = lane & 15;
    int row_base = blockIdx.x * 64;

    for (int i = tid; i < 1024; i += 256) {                     // stage 64x64 fp32 -> fp16
        f32x4 v = *(const f32x4*)(inputs + (size_t)row_base * DDIM + (size_t)i * 4);
        int row = i >> 4, d4 = (i & 15) * 4;
        half4 h; h[0]=(_Float16)v[0]; h[1]=(_Float16)v[1]; h[2]=(_Float16)v[2]; h[3]=(_Float16)v[3];
        *(half4*)(in_s + row * 72 + d4) = h;
    }
    __syncthreads();

    half8 a0 = *(const half8*)(in_s + (w * 16 + c) * 72 + q * 8);
    half8 a1 = *(const half8*)(in_s + (w * 16 + c) * 72 + 32 + q * 8);
    int row = row_base + w * 16 + q * 4;
    #pragma unroll 4
    for (int ntg = 0; ntg < 32; ++ntg) {
        int n = ntg * 16 + c;
        half8 b0 = *(const half8*)(tail + WI_OFF + ((size_t)ntg * 64 + lane) * 8);
        half8 b1 = *(const half8*)(tail + WI_OFF + ((size_t)(32 + ntg) * 64 + lane) * 8);
        float bv  = b_in[n];
        float brv = b_res[n];
        f32x4 acc = {bv, bv, bv, bv};
        acc = __builtin_amdgcn_mfma_f32_16x16x32_f16(a0, b0, acc, 0, 0, 0);
        acc = __builtin_amdgcn_mfma_f32_16x16x32_f16(a1, b1, acc, 0, 0, 0);
        #pragma unroll
        for (int r = 0; r < 4; ++r) {
            float o = acc[r] + ((((row + r) & (T_STEPS - 1)) != 0) ? brv : 0.f);
            U[(size_t)(row + r) * NDIM + n] = o;
        }
    }
}

// ---------------------------------------------------------------------------
// scan: 32 persistent blocks (one CU each), 512 threads (8 waves).
// Round-3 change: each block owns 8 batches (was 16). MFMA B-operand slots
// 8..15 carry duplicate columns (lanes c>=8 mirror c-8); those lanes are
// exec-masked off all stores. Per-CU global stream halves (64->32 KB/step):
// the per-CU VMEM path was at ~9 B/cyc (~m13's per-CU ceiling) and the
// twice-per-step vmcnt drain was eating the store-queue tail. x_lds shrinks
// to 8 rows; lanes (c, c+8) read identical x addresses -> LDS broadcast.
// Kept: W_res k-tiles 0..3 in LDS / 4..15 in regs, xprev-in-registers,
// b_res folded into U, clamp-free tanh, plain __syncthreads().
// ---------------------------------------------------------------------------
__global__ __launch_bounds__(512, 2) void scan_kernel(
        const float* __restrict__ W_res,
        const _Float16* __restrict__ tail, float* __restrict__ out) {
    __shared__ _Float16 W_lds[NDIM * WLDS_STRIDE];   // [ncol][k'] k' in [0,128)
    __shared__ _Float16 x_lds[BPB * XLDS_STRIDE];    // [batch][k=ncol] fp16 state

    int tid = threadIdx.x;
    int w = tid >> 6, lane = tid & 63, q = lane >> 4, c = lane & 15;
    int b0 = blockIdx.x * BPB;
    int cb = c & (BPB - 1);             // batch sub-index (lanes c>=8 mirror c-8)
    bool act = (c < BPB);               // only these lanes own real output

    for (int idx = tid; idx < 128 * NDIM; idx += 512) {          // W_res k<128 -> LDS
        int k = idx >> 9, n = idx & 511;
        W_lds[n * WLDS_STRIDE + k] = (_Float16)W_res[idx];
    }
    for (int i = tid; i < BPB * XLDS_STRIDE; i += 512) x_lds[i] = (_Float16)0.f;

    half8 wreg[12][4];                                           // W_res k-tiles 4..15
    #pragma unroll
    for (int ktr = 0; ktr < 12; ++ktr)
        #pragma unroll
        for (int mt = 0; mt < 4; ++mt)
            wreg[ktr][mt] = *(const half8*)(tail + RF_OFF +
                ((size_t)(ktr * 32 + (w * 4 + mt)) * 64 + lane) * 8);

    int batch = b0 + cb;                // valid for ALL lanes (duplicated c>=8)
    int nbase = w * 64 + q * 4;         // + mt*16 + r = global n-col
    size_t outb = (size_t)batch * T_STEPS * NDIM;

    f32x4 Upre[4];
    #pragma unroll
    for (int mt = 0; mt < 4; ++mt)
        Upre[mt] = *(const f32x4*)(out + outb + nbase + mt * 16);   // U[b][0][*]

    half4 xprev[4];                     // this lane's own x state (fp16-rounded)
    #pragma unroll
    for (int mt = 0; mt < 4; ++mt)
        #pragma unroll
        for (int r = 0; r < 4; ++r) xprev[mt][r] = (_Float16)0.f;

    __syncthreads();

    for (int t = 0; t < T_STEPS; ++t) {
        f32x4 acc[4];
        #pragma unroll
        for (int mt = 0; mt < 4; ++mt) acc[mt] = Upre[mt];       // b_res pre-folded
        if (t < T_STEPS - 1) {                                   // prefetch U[t+1]
            #pragma unroll
            for (int mt = 0; mt < 4; ++mt)
                Upre[mt] = *(const f32x4*)(out + outb + (size_t)(t + 1) * NDIM + nbase + mt * 16);
        }
        #pragma unroll
        for (int kt = 0; kt < 4; ++kt) {                         // LDS-resident k-tiles
            half8 xb = *(const half8*)(x_lds + cb * XLDS_STRIDE + kt * 32 + q * 8);
            #pragma unroll
            for (int mt = 0; mt < 4; ++mt) {
                half8 a = *(const half8*)(W_lds +
                    (size_t)((w * 4 + mt) * 16 + c) * WLDS_STRIDE + kt * 32 + q * 8);
                acc[mt] = __builtin_amdgcn_mfma_f32_16x16x32_f16(a, xb, acc[mt], 0, 0, 0);
            }
        }
        #pragma unroll
        for (int ktr = 0; ktr < 12; ++ktr) {                     // register k-tiles
            half8 xb = *(const half8*)(x_lds + cb * XLDS_STRIDE + (ktr + 4) * 32 + q * 8);
            #pragma unroll
            for (int mt = 0; mt < 4; ++mt)
                acc[mt] = __builtin_amdgcn_mfma_f32_16x16x32_f16(wreg[ktr][mt], xb, acc[mt], 0, 0, 0);
        }
        // epilogue: blend + tanh; store X (active lanes only); x_prev in regs
        #pragma unroll
        for (int mt = 0; mt < 4; ++mt) {
            f32x4 xn;
            #pragma unroll
            for (int r = 0; r < 4; ++r)
                xn[r] = 0.5f * ((float)xprev[mt][r] + tanh_fast(acc[mt][r]));
            if (act) {
                *(f32x4*)(out + outb + (size_t)t * NDIM + nbase + mt * 16) = xn;
                if (t == T_STEPS - 1)
                    *(f32x4*)(out + (size_t)BBATCH * T_STEPS * NDIM +
                              (size_t)batch * NDIM + nbase + mt * 16) = xn;
            }
            #pragma unroll
            for (int r = 0; r < 4; ++r) xprev[mt][r] = (_Float16)xn[r];
        }
        __syncthreads();                                          // all reads of x done
        if (act) {
            #pragma unroll
            for (int mt = 0; mt < 4; ++mt)
                *(half4*)(x_lds + cb * XLDS_STRIDE + nbase + mt * 16) = xprev[mt];
        }
        __syncthreads();                                          // x published
    }
}

extern "C" void kernel_launch(void* const* d_in, const int* in_sizes, int n_in,
                              void* d_out, int out_size, void* d_ws, size_t ws_size,
                              hipStream_t stream) {
    const float* inputs = (const float*)d_in[0];
    const float* W_in   = (const float*)d_in[1];
    const float* b_in   = (const float*)d_in[2];
    const float* W_res  = (const float*)d_in[3];
    const float* b_res  = (const float*)d_in[4];
    float* out = (float*)d_out;
    // fragment scratch lives in the final-state tail of d_out (rewritten at t=511)
    _Float16* tail = (_Float16*)(out + (size_t)BBATCH * T_STEPS * NDIM);

    prep_kernel<<<96, 256, 0, stream>>>(W_in, W_res, tail);
    u_kernel<<<(BBATCH * T_STEPS) / 64, 256, 0, stream>>>(inputs, b_in, b_res, tail, out);
    scan_kernel<<<BBATCH / BPB, 512, 0, stream>>>(W_res, tail, out);
}